// Round 1
// baseline (568.919 us; speedup 1.0000x reference)
//
#include <hip/hip_runtime.h>

#define DIN 128
#define HDIM 64

// ---- degree count: deg[dst] += 1 per edge ----
__global__ __launch_bounds__(256) void k_deg(const int* __restrict__ dst,
                                             float* __restrict__ degf, int E) {
    int i = blockIdx.x * 256 + threadIdx.x;
    if (i < E) atomicAdd(&degf[dst[i]], 1.0f);
}

// ---- dinv[n] = rsqrt(deg[n] + 1)  (self-loop ensures deg>0) ----
__global__ __launch_bounds__(256) void k_dinv(float* __restrict__ degf, int n) {
    int i = blockIdx.x * 256 + threadIdx.x;
    if (i < n) degf[i] = rsqrtf(degf[i] + 1.0f);
}

// ---- hs[n] = (x[n] @ W1^T) * dinv[n] ----
// LDS holds W1 as [k4][h] float4 groups: lds[(k4*64 + h)*4 + j] = W1[h][k4*4+j]
__global__ __launch_bounds__(256) void k_h1(const float* __restrict__ x,
                                            const float* __restrict__ W1,
                                            const float* __restrict__ dinv,
                                            float* __restrict__ hs, int n) {
    __shared__ float W1t[DIN * HDIM];
    int tid = threadIdx.x;
    for (int i = tid; i < DIN * HDIM; i += 256) {
        int h = i >> 7, k = i & 127;
        W1t[((k >> 2) * HDIM + h) * 4 + (k & 3)] = W1[i];
    }
    __syncthreads();
    const float4* W1t4 = (const float4*)W1t;
    int lane = tid & 63;
    int wave = tid >> 6;
    const int NPW = 16;  // nodes per wave
    int base = blockIdx.x * (NPW * 4) + wave * NPW;
    for (int nn = 0; nn < NPW; ++nn) {
        int node = base + nn;
        if (node >= n) break;
        const float4* xr = (const float4*)(x + (size_t)node * DIN);
        float acc = 0.f;
        #pragma unroll
        for (int k4 = 0; k4 < DIN / 4; ++k4) {
            float4 xv = xr[k4];
            float4 w = W1t4[k4 * HDIM + lane];
            acc += xv.x * w.x + xv.y * w.y + xv.z * w.z + xv.w * w.w;
        }
        hs[(size_t)node * HDIM + lane] = acc * dinv[node];
    }
}

// ---- scatter: accum[dst] += hs[src], one wave per edge ----
__global__ __launch_bounds__(256) void k_scatter(const int* __restrict__ src,
                                                 const int* __restrict__ dst,
                                                 const float* __restrict__ hs,
                                                 float* __restrict__ accum, int E) {
    int e = blockIdx.x * 4 + (threadIdx.x >> 6);
    int lane = threadIdx.x & 63;
    if (e < E) {
        int s = src[e], d = dst[e];
        atomicAdd(&accum[(size_t)d * HDIM + lane], hs[(size_t)s * HDIM + lane]);
    }
}

// ---- finalize: h = relu(dinv*(accum+hs) + b1); out = (h@Wmu^T+bmu, h@Wlv^T+blv) ----
__global__ __launch_bounds__(256) void k_final(const float* __restrict__ accum,
                                               const float* __restrict__ hs,
                                               const float* __restrict__ dinv,
                                               const float* __restrict__ b1,
                                               const float* __restrict__ Wmu,
                                               const float* __restrict__ bmu,
                                               const float* __restrict__ Wlv,
                                               const float* __restrict__ blv,
                                               float* __restrict__ out, int n) {
    __shared__ float WmuT[HDIM * HDIM];  // [j][o]
    __shared__ float WlvT[HDIM * HDIM];
    int tid = threadIdx.x;
    for (int i = tid; i < HDIM * HDIM; i += 256) {
        int o = i >> 6, j = i & 63;
        WmuT[j * HDIM + o] = Wmu[i];
        WlvT[j * HDIM + o] = Wlv[i];
    }
    __syncthreads();
    int lane = tid & 63;
    int wave = tid >> 6;
    float bm = bmu[lane], bl = blv[lane], bb = b1[lane];
    const int NPW = 16;
    int base = blockIdx.x * (NPW * 4) + wave * NPW;
    for (int nn = 0; nn < NPW; ++nn) {
        int node = base + nn;
        if (node >= n) break;
        size_t idx = (size_t)node * HDIM + lane;
        float h = (accum[idx] + hs[idx]) * dinv[node] + bb;
        h = fmaxf(h, 0.f);
        float mu = bm, lv = bl;
        #pragma unroll
        for (int j = 0; j < HDIM; ++j) {
            float hj = __shfl(h, j);
            mu += hj * WmuT[j * HDIM + lane];
            lv += hj * WlvT[j * HDIM + lane];
        }
        out[idx] = mu;
        out[(size_t)n * HDIM + idx] = lv;
    }
}

extern "C" void kernel_launch(void* const* d_in, const int* in_sizes, int n_in,
                              void* d_out, int out_size, void* d_ws, size_t ws_size,
                              hipStream_t stream) {
    const float* x   = (const float*)d_in[0];
    const int*   ei  = (const int*)d_in[1];
    const float* W1  = (const float*)d_in[2];
    const float* b1  = (const float*)d_in[3];
    const float* Wmu = (const float*)d_in[4];
    const float* bmu = (const float*)d_in[5];
    const float* Wlv = (const float*)d_in[6];
    const float* blv = (const float*)d_in[7];
    float* out = (float*)d_out;

    const int N = in_sizes[0] / DIN;   // 100000
    const int E = in_sizes[1] / 2;     // 1000000
    const int* src = ei;
    const int* dst = ei + E;

    char* ws = (char*)d_ws;
    size_t degBytes = ((size_t)N * sizeof(float) + 255) & ~(size_t)255;
    float* degf  = (float*)ws;                         // N floats (becomes dinv)
    float* hs    = (float*)(ws + degBytes);            // N*64 floats
    float* accum = hs + (size_t)N * HDIM;              // N*64 floats

    hipMemsetAsync(degf, 0, (size_t)N * sizeof(float), stream);
    hipMemsetAsync(accum, 0, (size_t)N * HDIM * sizeof(float), stream);

    k_deg<<<(E + 255) / 256, 256, 0, stream>>>(dst, degf, E);
    k_dinv<<<(N + 255) / 256, 256, 0, stream>>>(degf, N);
    k_h1<<<(N + 63) / 64, 256, 0, stream>>>(x, W1, degf, hs, N);
    k_scatter<<<(E + 3) / 4, 256, 0, stream>>>(src, dst, hs, accum, E);
    k_final<<<(N + 63) / 64, 256, 0, stream>>>(accum, hs, degf, b1, Wmu, bmu,
                                               Wlv, blv, out, N);
}

// Round 2
// 433.520 us; speedup vs baseline: 1.3123x; 1.3123x over previous
//
#include <hip/hip_runtime.h>

#define DIN 128
#define HDIM 64

// ---- histogram: cnt[dst]++ per edge (int atomics) ----
__global__ __launch_bounds__(256) void k_hist(const int* __restrict__ dst,
                                              int* __restrict__ cnt, int E) {
    int i = blockIdx.x * 256 + threadIdx.x;
    if (i < E) atomicAdd(&cnt[dst[i]], 1);
}

// ---- scan A: per-block (1024) exclusive scan of cnt; block totals to bsum ----
__global__ __launch_bounds__(1024) void k_scanA(const int* __restrict__ cnt,
                                                int* __restrict__ excl,
                                                int* __restrict__ bsum, int n) {
    __shared__ int wsum[16];
    int t = threadIdx.x;
    int g = blockIdx.x * 1024 + t;
    int v = (g < n) ? cnt[g] : 0;
    int lane = t & 63, w = t >> 6;
    int s = v;
    #pragma unroll
    for (int d = 1; d < 64; d <<= 1) {
        int u = __shfl_up(s, d);
        if (lane >= d) s += u;
    }
    if (lane == 63) wsum[w] = s;
    __syncthreads();
    if (w == 0 && lane < 16) {
        int ws = wsum[lane];
        #pragma unroll
        for (int d = 1; d < 16; d <<= 1) {
            int u = __shfl_up(ws, d);
            if (lane >= d) ws += u;
        }
        wsum[lane] = ws;
    }
    __syncthreads();
    int base = (w > 0) ? wsum[w - 1] : 0;
    int incl = base + s;
    if (g < n) excl[g] = incl - v;
    if (t == 1023) bsum[blockIdx.x] = incl;
}

// ---- scan B: exclusive scan of block sums (single wave) ----
__global__ __launch_bounds__(64) void k_scanB(int* __restrict__ bsum, int nb) {
    int lane = threadIdx.x;
    int run = 0;
    for (int c = 0; c < nb; c += 64) {
        int i = c + lane;
        int v = (i < nb) ? bsum[i] : 0;
        int s = v;
        #pragma unroll
        for (int d = 1; d < 64; d <<= 1) {
            int u = __shfl_up(s, d);
            if (lane >= d) s += u;
        }
        if (i < nb) bsum[i] = run + s - v;
        run += __shfl(s, 63);
    }
}

// ---- scan C: offsets = excl + bsum[blk]; cursor copy; dinv = rsqrt(cnt+1) ----
__global__ __launch_bounds__(256) void k_scanC(const int* __restrict__ excl,
                                               const int* __restrict__ bsum,
                                               const int* __restrict__ cnt,
                                               int* __restrict__ offsets,
                                               int* __restrict__ cursor,
                                               float* __restrict__ dinv, int n) {
    int g = blockIdx.x * 256 + threadIdx.x;
    if (g < n) {
        int o = excl[g] + bsum[g >> 10];
        offsets[g] = o;
        cursor[g] = o;
        dinv[g] = rsqrtf((float)cnt[g] + 1.0f);
    }
}

// ---- reorder: srcSorted[cursor[dst]++] = src ----
__global__ __launch_bounds__(256) void k_reorder(const int* __restrict__ src,
                                                 const int* __restrict__ dst,
                                                 int* __restrict__ cursor,
                                                 int* __restrict__ srcSorted, int E) {
    int e = blockIdx.x * 256 + threadIdx.x;
    if (e < E) {
        int d = dst[e];
        int p = atomicAdd(&cursor[d], 1);
        srcSorted[p] = src[e];
    }
}

// ---- hs[n] = (x[n] @ W1^T) * dinv[n] ----
__global__ __launch_bounds__(256) void k_h1(const float* __restrict__ x,
                                            const float* __restrict__ W1,
                                            const float* __restrict__ dinv,
                                            float* __restrict__ hs, int n) {
    __shared__ float W1t[DIN * HDIM];
    int tid = threadIdx.x;
    for (int i = tid; i < DIN * HDIM; i += 256) {
        int h = i >> 7, k = i & 127;
        W1t[((k >> 2) * HDIM + h) * 4 + (k & 3)] = W1[i];
    }
    __syncthreads();
    const float4* W1t4 = (const float4*)W1t;
    int lane = tid & 63;
    int wave = tid >> 6;
    const int NPW = 16;  // nodes per wave
    int base = blockIdx.x * (NPW * 4) + wave * NPW;
    for (int nn = 0; nn < NPW; ++nn) {
        int node = base + nn;
        if (node >= n) break;
        const float4* xr = (const float4*)(x + (size_t)node * DIN);
        float acc = 0.f;
        #pragma unroll
        for (int k4 = 0; k4 < DIN / 4; ++k4) {
            float4 xv = xr[k4];
            float4 w = W1t4[k4 * HDIM + lane];
            acc += xv.x * w.x + xv.y * w.y + xv.z * w.z + xv.w * w.w;
        }
        hs[(size_t)node * HDIM + lane] = acc * dinv[node];
    }
}

// ---- fused gather-aggregate + relu + dual GEMV ----
__global__ __launch_bounds__(256) void k_aggfinal(const int* __restrict__ offsets,
                                                  const int* __restrict__ cnt,
                                                  const int* __restrict__ srcSorted,
                                                  const float* __restrict__ hs,
                                                  const float* __restrict__ dinv,
                                                  const float* __restrict__ b1,
                                                  const float* __restrict__ Wmu,
                                                  const float* __restrict__ bmu,
                                                  const float* __restrict__ Wlv,
                                                  const float* __restrict__ blv,
                                                  float* __restrict__ out, int n) {
    __shared__ float WmuT[HDIM * HDIM];  // [j][o]
    __shared__ float WlvT[HDIM * HDIM];
    int tid = threadIdx.x;
    for (int i = tid; i < HDIM * HDIM; i += 256) {
        int o = i >> 6, j = i & 63;
        WmuT[j * HDIM + o] = Wmu[i];
        WlvT[j * HDIM + o] = Wlv[i];
    }
    __syncthreads();
    int lane = tid & 63;
    int wave = tid >> 6;
    float bb = b1[lane], bm = bmu[lane], bl = blv[lane];
    const int NPW = 8;
    int base = blockIdx.x * (NPW * 4) + wave * NPW;
    for (int nn = 0; nn < NPW; ++nn) {
        int node = base + nn;
        if (node >= n) break;
        int start = offsets[node];
        int c = cnt[node];
        float a0 = hs[(size_t)node * HDIM + lane];  // self-loop term
        float a1 = 0.f, a2 = 0.f, a3 = 0.f;
        for (int i = 0; i < c; i += 64) {
            int m = c - i;
            if (m > 64) m = 64;
            int sv = (lane < m) ? srcSorted[start + i + lane] : 0;
            int k = 0;
            for (; k + 4 <= m; k += 4) {
                int s0 = __shfl(sv, k), s1 = __shfl(sv, k + 1);
                int s2 = __shfl(sv, k + 2), s3 = __shfl(sv, k + 3);
                float v0 = hs[(size_t)s0 * HDIM + lane];
                float v1 = hs[(size_t)s1 * HDIM + lane];
                float v2 = hs[(size_t)s2 * HDIM + lane];
                float v3 = hs[(size_t)s3 * HDIM + lane];
                a0 += v0; a1 += v1; a2 += v2; a3 += v3;
            }
            for (; k < m; ++k) {
                int s = __shfl(sv, k);
                a0 += hs[(size_t)s * HDIM + lane];
            }
        }
        float h = fmaxf((a0 + a1 + a2 + a3) * dinv[node] + bb, 0.f);
        float mu = bm, lv = bl;
        #pragma unroll
        for (int j = 0; j < HDIM; ++j) {
            float hj = __shfl(h, j);
            mu += hj * WmuT[j * HDIM + lane];
            lv += hj * WlvT[j * HDIM + lane];
        }
        size_t idx = (size_t)node * HDIM + lane;
        out[idx] = mu;
        out[(size_t)n * HDIM + idx] = lv;
    }
}

extern "C" void kernel_launch(void* const* d_in, const int* in_sizes, int n_in,
                              void* d_out, int out_size, void* d_ws, size_t ws_size,
                              hipStream_t stream) {
    const float* x   = (const float*)d_in[0];
    const int*   ei  = (const int*)d_in[1];
    const float* W1  = (const float*)d_in[2];
    const float* b1  = (const float*)d_in[3];
    const float* Wmu = (const float*)d_in[4];
    const float* bmu = (const float*)d_in[5];
    const float* Wlv = (const float*)d_in[6];
    const float* blv = (const float*)d_in[7];
    float* out = (float*)d_out;

    const int N = in_sizes[0] / DIN;   // 100000
    const int E = in_sizes[1] / 2;     // 1000000
    const int* src = ei;
    const int* dst = ei + E;

    auto align256 = [](size_t b) { return (b + 255) & ~(size_t)255; };
    char* ws = (char*)d_ws;
    size_t off = 0;
    float* dinv    = (float*)(ws + off); off += align256((size_t)N * 4);
    int*   cnt     = (int*)  (ws + off); off += align256((size_t)N * 4);
    int*   excl    = (int*)  (ws + off); off += align256((size_t)N * 4);
    int*   offsets = (int*)  (ws + off); off += align256((size_t)N * 4);
    int*   cursor  = (int*)  (ws + off); off += align256((size_t)N * 4);
    int*   bsum    = (int*)  (ws + off); off += align256(128 * 4);
    int*   srcSorted = (int*)(ws + off); off += align256((size_t)E * 4);
    float* hs      = (float*)(ws + off); off += align256((size_t)N * HDIM * 4);

    hipMemsetAsync(cnt, 0, (size_t)N * sizeof(int), stream);

    const int nb = (N + 1023) / 1024;
    k_hist<<<(E + 255) / 256, 256, 0, stream>>>(dst, cnt, E);
    k_scanA<<<nb, 1024, 0, stream>>>(cnt, excl, bsum, N);
    k_scanB<<<1, 64, 0, stream>>>(bsum, nb);
    k_scanC<<<(N + 255) / 256, 256, 0, stream>>>(excl, bsum, cnt, offsets, cursor, dinv, N);
    k_reorder<<<(E + 255) / 256, 256, 0, stream>>>(src, dst, cursor, srcSorted, E);
    k_h1<<<(N + 63) / 64, 256, 0, stream>>>(x, W1, dinv, hs, N);
    k_aggfinal<<<(N + 31) / 32, 256, 0, stream>>>(offsets, cnt, srcSorted, hs, dinv,
                                                  b1, Wmu, bmu, Wlv, blv, out, N);
}